// Round 3
// baseline (190.182 us; speedup 1.0000x reference)
//
#include <hip/hip_runtime.h>
#include <hip/hip_bf16.h>
#include <math.h>

#define N_ROI 8192
#define C_IN  1024
#define HIDD  256
#define FGD   64
#define CLSD  128
#define INV_TAU 5.0f
#define SCALE_LOG2E 7.2134752f   // 5 * log2(e)
#define LN2F 0.69314718f

using frag_ab = __attribute__((ext_vector_type(8))) short;   // 8 bf16 = 4 VGPRs
using f32x16  = __attribute__((ext_vector_type(16))) float;

static __device__ __forceinline__ short f32_to_bf16_bits(float f) {
  unsigned u = __builtin_bit_cast(unsigned, f);
  u = (u + 0x7FFFu + ((u >> 16) & 1u)) >> 16;   // RNE (inputs finite)
  return (short)u;
}
static __device__ __forceinline__ float bf16_bits_to_f32(short b) {
  unsigned u = ((unsigned)(unsigned short)b) << 16;
  return __builtin_bit_cast(float, u);
}
static __device__ __forceinline__ float fast_exp2(float x) {
#if __has_builtin(__builtin_amdgcn_exp2f)
  return __builtin_amdgcn_exp2f(x);
#else
  return exp2f(x);
#endif
}
// async global->LDS, 16B per lane. LDS dest = wave-uniform base + lane*16.
static __device__ __forceinline__ void async_copy16(const void* g, void* l) {
  __builtin_amdgcn_global_load_lds(
      (const __attribute__((address_space(1))) unsigned int*)g,
      (__attribute__((address_space(3))) unsigned int*)l, 16, 0, 0);
}

// ---------------- L1: pack weights (fp32 -> bf16 frag order) + zero accum/cnt ------
__global__ __launch_bounds__(256) void pack_zero_kernel(
    const float* __restrict__ w1f, const float* __restrict__ w1c,
    const float* __restrict__ w2f, const float* __restrict__ w2c,
    short* __restrict__ W1pf, short* __restrict__ W1pc,
    short* __restrict__ W2pf, short* __restrict__ W2pc,
    float* __restrict__ accum, int* __restrict__ cnt) {
  int b = blockIdx.x;
  if (b == 280) {
    int t = threadIdx.x;
    if (t < 8) accum[t] = 0.f;
    if (t < 24) cnt[t] = 0;
    return;
  }
  const float* src; short* dst; int Ksh; int b0;
  if (b < 128)      { src = w1f; dst = W1pf; Ksh = 10; b0 = 0; }
  else if (b < 256) { src = w1c; dst = W1pc; Ksh = 10; b0 = 128; }
  else if (b < 264) { src = w2f; dst = W2pf; Ksh = 8;  b0 = 256; }
  else              { src = w2c; dst = W2pc; Ksh = 8;  b0 = 264; }
  int K = 1 << Ksh;
  int f = (b - b0) * 256 + threadIdx.x;
  int r = f >> (Ksh - 3);
  int c0 = (f & ((K >> 3) - 1)) << 3;
  float4 v0 = *(const float4*)(src + (size_t)r * K + c0);
  float4 v1 = *(const float4*)(src + (size_t)r * K + c0 + 4);
  union { short s[8]; uint4 v; } o;
  o.s[0] = f32_to_bf16_bits(v0.x); o.s[1] = f32_to_bf16_bits(v0.y);
  o.s[2] = f32_to_bf16_bits(v0.z); o.s[3] = f32_to_bf16_bits(v0.w);
  o.s[4] = f32_to_bf16_bits(v1.x); o.s[5] = f32_to_bf16_bits(v1.y);
  o.s[6] = f32_to_bf16_bits(v1.z); o.s[7] = f32_to_bf16_bits(v1.w);
  ((uint4*)dst)[(size_t)((r >> 5) * (K >> 4) + (c0 >> 4)) * 64 +
                ((c0 >> 3) & 1) * 32 + (r & 31)] = o.v;
}

// ---------------- phase-2 helper: gemm2+normalize+pack from LDS H tile ----------
// Single wave, no barriers. T2 row-major H: T2[r*264 + c], c in [0,256).
template<int D>
__device__ __forceinline__ void gemm2_from_lds(
    const short* __restrict__ T2,
    const short* __restrict__ W2p, const float* __restrict__ b2,
    short* __restrict__ Zr, float* __restrict__ tii,
    short* __restrict__ T, int gt) {
  int lane = threadIdx.x & 63;
  const frag_ab* Wv = (const frag_ab*)W2p;
  constexpr int NT = D / 32;
  frag_ab a[16];
  #pragma unroll
  for (int kc = 0; kc < 16; ++kc)
    a[kc] = *(const frag_ab*)&T2[(lane & 31) * 264 + kc * 16 + (lane >> 5) * 8];
  f32x16 acc[NT];
  #pragma unroll
  for (int j = 0; j < NT; ++j)
    #pragma unroll
    for (int q = 0; q < 16; ++q) acc[j][q] = 0.f;
  #pragma unroll
  for (int kc = 0; kc < 16; ++kc)
    #pragma unroll
    for (int j = 0; j < NT; ++j)
      acc[j] = __builtin_amdgcn_mfma_f32_32x32x16_bf16(a[kc], Wv[(j * 16 + kc) * 64 + lane], acc[j], 0, 0, 0);
  int c = lane & 31, h = lane >> 5;
  float bb[NT];
  #pragma unroll
  for (int j = 0; j < NT; ++j) bb[j] = b2[j * 32 + c];
  float s1[16];
  #pragma unroll
  for (int r = 0; r < 16; ++r) {
    s1[r] = 0.f;
    #pragma unroll
    for (int j = 0; j < NT; ++j) {
      float v = acc[j][r] + bb[j];
      s1[r] += v * v;
    }
  }
  #pragma unroll
  for (int r = 0; r < 16; ++r)
    #pragma unroll
    for (int m = 1; m < 32; m <<= 1) s1[r] += __shfl_xor(s1[r], m);
  float s2[16];
  #pragma unroll
  for (int r = 0; r < 16; ++r) s2[r] = 0.f;
  #pragma unroll
  for (int j = 0; j < NT; ++j) {
    int cl = j * 32 + c;
    #pragma unroll
    for (int g = 0; g < 4; ++g) {
      short q0, q1, q2, q3;
      #pragma unroll
      for (int e = 0; e < 4; ++e) {
        int r = g * 4 + e;
        float sc = 1.f / fmaxf(sqrtf(s1[r]), 1e-8f);
        short qb = f32_to_bf16_bits((acc[j][r] + bb[j]) * sc);
        float zf = bf16_bits_to_f32(qb);
        s2[r] += zf * zf;
        if (e == 0) q0 = qb; else if (e == 1) q1 = qb; else if (e == 2) q2 = qb; else q3 = qb;
      }
      *(short4*)&T[cl * 36 + 4 * h + 8 * g] = make_short4(q0, q1, q2, q3);
    }
  }
  #pragma unroll
  for (int r = 0; r < 16; ++r)
    #pragma unroll
    for (int m = 1; m < 32; m <<= 1) s2[r] += __shfl_xor(s2[r], m);
  if (c == 0) {
    #pragma unroll
    for (int r = 0; r < 16; ++r)
      tii[gt * 32 + (r & 3) + 8 * (r >> 2) + 4 * h] = s2[r];
  }
  uint4* Zv = (uint4*)Zr;
  #pragma unroll
  for (int k = 0; k < D / 16; ++k) {
    int c0 = (2 * k + h) * 8;
    union { short s[8]; uint4 u; } o;
    #pragma unroll
    for (int e = 0; e < 8; ++e) o.s[e] = T[(c0 + e) * 36 + c];
    Zv[(size_t)(gt * (D / 16) + k) * 64 + h * 32 + c] = o.u;
  }
}

// ---------------- L2: fused MLP, head-split: grid (256 row-tiles x 2 heads) ------
__global__ __launch_bounds__(256) void fused_mlp_kernel(
    const float* __restrict__ X,
    const short* __restrict__ W1pf, const short* __restrict__ W1pc,
    const float* __restrict__ b1f, const float* __restrict__ b1c,
    const short* __restrict__ W2pf, const short* __restrict__ W2pc,
    const float* __restrict__ b2f, const float* __restrict__ b2c,
    short* __restrict__ Zrf, short* __restrict__ Zrc,
    float* __restrict__ tiif, float* __restrict__ tiic,
    const int* __restrict__ labels,
    float* __restrict__ Sfg, float* __restrict__ Pfg,
    float* __restrict__ Scls, float* __restrict__ SPc,
    float* __restrict__ pfv, float* __restrict__ nimv,
    float* __restrict__ ljmv, int* __restrict__ cnt) {
  __shared__ short stageA[2][1024];     // 4 KB
  __shared__ short T2[32 * 264];        // 16.9 KB row-major H (this head)
  __shared__ short Tw[128 * 36];        // 9.2 KB phase-2 transpose
  int tid = threadIdx.x, lane = tid & 63, wv = tid >> 6;
  int Mb = blockIdx.x, head = blockIdx.y;

  if (head == 0 && tid < 32) {
    int i = Mb * 32 + tid;
    Sfg[i] = 0.f; Pfg[i] = 0.f; Scls[i] = 0.f; SPc[i] = 0.f;
    int l = labels[i];
    pfv[i]  = (l > 0)  ? 1.f : 0.f;
    nimv[i] = (l != -1) ? 1.f : 0.f;
    ljmv[i] = (l > 0)  ? (float)l : -7.f;
    int b = l + 1; if (b < 0) b = 0; if (b > 21) b = 21;
    atomicAdd(&cnt[b], 1);
  }

  const short* Wp = head ? W1pc : W1pf;
  const float* b1 = head ? b1c  : b1f;
  const uint4* Wv4 = (const uint4*)Wp;
  int arow = tid >> 3;
  int ac4  = tid & 7;
  const float* Xp = X + (size_t)(Mb * 32 + arow) * C_IN + ac4 * 4;
  int aslot = ((ac4 >> 2) * 64 + ((ac4 >> 1) & 1) * 32 + arow) * 8 + (ac4 & 1) * 4;

  float4 av;
  frag_ab breg[2][4];                   // [bank][kci*2+nt], 64-col strip
  f32x16 acc[2];
  #pragma unroll
  for (int nt = 0; nt < 2; ++nt)
    #pragma unroll
    for (int q = 0; q < 16; ++q) acc[nt][q] = 0.f;

  auto loadA = [&](int c) { av = *(const float4*)(Xp + c * 32); };
  auto loadB = [&](int c, int s) {
    #pragma unroll
    for (int kci = 0; kci < 2; ++kci)
      #pragma unroll
      for (int nt = 0; nt < 2; ++nt)
        breg[s][kci * 2 + nt] =
            *(const frag_ab*)&Wv4[(size_t)((wv * 2 + nt) * 64 + c * 2 + kci) * 64 + lane];
  };
  auto storeA = [&](int buf) {
    *(short4*)&stageA[buf][aslot] =
        make_short4(f32_to_bf16_bits(av.x), f32_to_bf16_bits(av.y),
                    f32_to_bf16_bits(av.z), f32_to_bf16_bits(av.w));
  };
  auto domfma = [&](int buf, int bank) {
    frag_ab a0 = *(const frag_ab*)&stageA[buf][(0 * 64 + lane) * 8];
    frag_ab a1 = *(const frag_ab*)&stageA[buf][(1 * 64 + lane) * 8];
    #pragma unroll
    for (int nt = 0; nt < 2; ++nt)
      acc[nt] = __builtin_amdgcn_mfma_f32_32x32x16_bf16(a0, breg[bank][nt], acc[nt], 0, 0, 0);
    #pragma unroll
    for (int nt = 0; nt < 2; ++nt)
      acc[nt] = __builtin_amdgcn_mfma_f32_32x32x16_bf16(a1, breg[bank][2 + nt], acc[nt], 0, 0, 0);
  };

  loadA(0); loadB(0, 0); storeA(0);
  __syncthreads();
  for (int c = 0; c < 32; c += 2) {
    if (c + 1 < 32) { loadA(c + 1); loadB(c + 1, 1); }
    domfma(0, 0);
    if (c + 1 < 32) storeA(1);
    __syncthreads();
    if (c + 2 < 32) { loadA(c + 2); loadB(c + 2, 0); }
    domfma(1, 1);
    if (c + 2 < 32) storeA(0);
    __syncthreads();
  }
  {
    int cl31 = lane & 31, h = lane >> 5;
    #pragma unroll
    for (int nt = 0; nt < 2; ++nt) {
      int gc = wv * 64 + nt * 32 + cl31;
      float bb = b1[gc];
      #pragma unroll
      for (int q = 0; q < 16; ++q) {
        int row = (q & 3) + 8 * (q >> 2) + 4 * h;
        float x = fmaxf(acc[nt][q] + bb, 0.f);
        T2[row * 264 + gc] = f32_to_bf16_bits(x);
      }
    }
  }
  __syncthreads();

  if (wv == 0) {
    if (head == 0)
      gemm2_from_lds<FGD>(T2, W2pf, b2f, Zrf, tiif, Tw, Mb);
    else
      gemm2_from_lds<CLSD>(T2, W2pc, b2c, Zrc, tiic, Tw, Mb);
  }
}

// ---------------- L3: MFMA Gram loss — 512-thread blocks, 8 waves share tiles ----
// Each block: 8 waves x 1 i-tile = 256 i-rows; staged j-tiles shared by 8 waves
// (halves L2 traffic + barriers per Gram area vs 4-wave blocks). Stage quantum is
// 8 KB = 512 lanes x 16 B: one cls tile, or an fg tile PAIR (fg then runs two
// independent MFMA chains + 32 exps per iteration -> breaks the dependent-acc
// serialization). All waves issue exactly 1 global_load_lds per STAGE and per
// mask load (spare waves redundantly rewrite) so per-wave vmcnt counts stay
// uniform. 3 rotating buffers, counted vmcnt(1), one barrier per iteration.
template<int D, int MODE, int NJT>
__device__ __forceinline__ void loss_body(
    const short* __restrict__ Zr, const int* __restrict__ labels,
    const float* __restrict__ pfv, const float* __restrict__ nimv,
    const float* __restrict__ ljmv,
    float* __restrict__ Sg, float* __restrict__ Pg,
    short* __restrict__ smem) {
  constexpr int KC = D / 16;              // 4 (fg) or 8 (cls)
  constexpr int JP = (MODE == 0) ? 2 : 1; // j-tiles per iteration
  constexpr int NIT = NJT / JP;           // iterations: 8 (fg) or 16 (cls)
  constexpr int BUF_SH = 4096;            // shorts per 8 KB buffer
  int tid = threadIdx.x, lane = tid & 63, wv = tid >> 6;   // wv in 0..7
  int itile = (blockIdx.x >> 1) * 8 + wv;
  int jt0 = blockIdx.y * NJT;
  int jlane = lane & 31;
  const frag_ab* Zrv = (const frag_ab*)Zr;

  // A fragments (rescaled to log2-domain)
  frag_ab a[KC];
  #pragma unroll
  for (int kc = 0; kc < KC; ++kc) {
    frag_ab t = Zrv[(itile * KC + kc) * 64 + lane];
    #pragma unroll
    for (int e = 0; e < 8; ++e)
      t[e] = f32_to_bf16_bits(bf16_bits_to_f32(t[e]) * SCALE_LOG2E);
    a[kc] = t;
  }
  float limf[16];
  if (MODE == 1) {
    #pragma unroll
    for (int r = 0; r < 16; ++r) {
      int row = (r & 3) + 8 * (r >> 2) + 4 * (lane >> 5);
      limf[r] = (float)labels[itile * 32 + row];
    }
  }
  // Pin prologue register loads before the drain so later vmcnt counts are exact.
  __builtin_amdgcn_sched_barrier(0);
  asm volatile("s_waitcnt vmcnt(0)" ::: "memory");
  __builtin_amdgcn_sched_barrier(0);

  short* b0 = smem;
  short* b1 = smem + BUF_SH;
  short* b2 = smem + 2 * BUF_SH;
  float* maskf = (float*)(smem + 3 * BUF_SH);   // 512 (MODE0) / 1024 (MODE1) floats

  // stage masks: exactly 1 global_load_lds per wave (waves 2-7 / 4-7 redundant)
  if (MODE == 0) {
    async_copy16(pfv + jt0 * 32 + (size_t)(tid & 127) * 4,
                 maskf + (wv & 1) * 256);
  } else {
    const float* msrc = ((wv & 2) == 0) ? nimv : ljmv;
    float* mdst = maskf + ((wv & 2) ? 512 : 0) + (wv & 1) * 256;
    async_copy16(msrc + jt0 * 32 + (size_t)(tid & 127) * 4, mdst);
  }

  // stage iteration quantum: 8 KB linear (one cls tile / one fg tile pair)
  auto STAGE = [&](short* dst, int it) {
    const short* src = Zr + (size_t)(jt0 + it * JP) * KC * 512 / JP * JP;
    async_copy16(src + (size_t)tid * 8, dst + wv * 512);
  };

  STAGE(b0, 0); STAGE(b1, 1);

  float Ssum[16] = {}, Psum[16] = {};

  #pragma unroll 1
  for (int t = 0; t < NIT; ++t) {
    if (t < NIT - 1) asm volatile("s_waitcnt vmcnt(1)" ::: "memory");
    else             asm volatile("s_waitcnt vmcnt(0)" ::: "memory");
    __builtin_amdgcn_s_barrier();
    __builtin_amdgcn_sched_barrier(0);
    if (t + 2 < NIT) STAGE(b2, t + 2);

    if (MODE == 0) {
      float pf0 = maskf[t * 64 + jlane];
      float pf1 = maskf[t * 64 + 32 + jlane];
      f32x16 acc0, acc1;
      #pragma unroll
      for (int q = 0; q < 16; ++q) { acc0[q] = 0.f; acc1[q] = 0.f; }
      __builtin_amdgcn_s_setprio(1);
      #pragma unroll
      for (int kc = 0; kc < KC; ++kc) {
        frag_ab bb0 = *(const frag_ab*)&b0[(kc * 64 + lane) * 8];
        frag_ab bb1 = *(const frag_ab*)&b0[((KC + kc) * 64 + lane) * 8];
        acc0 = __builtin_amdgcn_mfma_f32_32x32x16_bf16(a[kc], bb0, acc0, 0, 0, 0);
        acc1 = __builtin_amdgcn_mfma_f32_32x32x16_bf16(a[kc], bb1, acc1, 0, 0, 0);
      }
      __builtin_amdgcn_s_setprio(0);
      #pragma unroll
      for (int rr = 0; rr < 16; ++rr) {
        float e0 = fast_exp2(acc0[rr]);
        float e1 = fast_exp2(acc1[rr]);
        Ssum[rr] += e0 + e1;
        Psum[rr] = fmaf(pf0, e0, fmaf(pf1, e1, Psum[rr]));
      }
    } else {
      float nim = maskf[t * 32 + jlane];
      float ljm = maskf[512 + t * 32 + jlane];
      f32x16 acc;
      #pragma unroll
      for (int q = 0; q < 16; ++q) acc[q] = 0.f;
      __builtin_amdgcn_s_setprio(1);
      #pragma unroll
      for (int kc = 0; kc < KC; ++kc) {
        frag_ab b = *(const frag_ab*)&b0[(kc * 64 + lane) * 8];
        acc = __builtin_amdgcn_mfma_f32_32x32x16_bf16(a[kc], b, acc, 0, 0, 0);
      }
      __builtin_amdgcn_s_setprio(0);
      #pragma unroll
      for (int rr = 0; rr < 16; ++rr) {
        float e = fast_exp2(acc[rr]);
        Ssum[rr] = fmaf(nim, e, Ssum[rr]);
        Psum[rr] += (limf[rr] == ljm) ? acc[rr] : 0.f;
      }
    }
    short* tmp = b0; b0 = b1; b1 = b2; b2 = tmp;   // rotate
  }

  #pragma unroll
  for (int r = 0; r < 16; ++r) {
    float s = Ssum[r], p = Psum[r];
    #pragma unroll
    for (int m = 1; m < 32; m <<= 1) { s += __shfl_xor(s, m); p += __shfl_xor(p, m); }
    if ((lane & 31) == 0) {
      if (MODE == 1) p *= LN2F;
      int row = (r & 3) + 8 * (r >> 2) + 4 * (lane >> 5);
      atomicAdd(&Sg[itile * 32 + row], s);
      atomicAdd(&Pg[itile * 32 + row], p);
    }
  }
}

__global__ __launch_bounds__(512, 2) void loss_kernel(
    const short* __restrict__ Zrf, const short* __restrict__ Zrc,
    const int* __restrict__ labels,
    const float* __restrict__ pfv, const float* __restrict__ nimv,
    const float* __restrict__ ljmv,
    float* __restrict__ Sfg, float* __restrict__ Pfg,
    float* __restrict__ Scls, float* __restrict__ SPc) {
  // 3 x 8 KB rotating buffers + mask region (1024 floats) = 28 KB
  __shared__ short smem[3 * 4096 + 2048];
  // mode interleaved on x (even=fg, odd=cls) so MFMA-heavy and exp-heavy blocks
  // co-reside on each CU for the whole kernel.
  if ((blockIdx.x & 1) == 0)
    loss_body<FGD, 0, 16>(Zrf, labels, pfv, nimv, ljmv, Sfg, Pfg, smem);
  else
    loss_body<CLSD, 1, 16>(Zrc, labels, pfv, nimv, ljmv, Scls, SPc, smem);
}

// ---------------- L4: per-row losses + weighted reduction + write-out ------------
__global__ __launch_bounds__(256) void finalize_kernel(
    const float* __restrict__ Sfg, const float* __restrict__ Pfg,
    const float* __restrict__ Scls, const float* __restrict__ SPc,
    const float* __restrict__ tiif, const float* __restrict__ tiic,
    const int* __restrict__ labels, const float* __restrict__ ious,
    int* __restrict__ cnt, float* __restrict__ accum, float* __restrict__ out) {
  int i = blockIdx.x * 256 + threadIdx.x;
  int l = labels[i];
  float iv = ious[i];
  float w = (iv > 0.5f) ? iv : 0.f;
  int cntP = 0;
  #pragma unroll
  for (int b = 2; b <= 21; ++b) cntP += cnt[b];
  int cntNI = N_ROI - cnt[0];
  bool Pi = (l > 0);
  float numF = 0.f, denF = 0.f, numC = 0.f, denC = 0.f;
  float eF = __expf(INV_TAU * tiif[i]);
  float Sf = Sfg[i] - eF;
  float Pf = Pfg[i] - (Pi ? eF : 0.f);
  int nposF = cntP - (Pi ? 1 : 0);
  if (Pi && nposF > 0) {
    float lossF = logf((Sf + 1e-8f) / (Pf + 1e-8f));
    numF = lossF * w; denF = w;
  }
  float tC = INV_TAU * tiic[i];
  float eC = __expf(tC);
  float Sc = Scls[i] - ((l != -1) ? eC : 0.f);
  float SP = SPc[i] - (Pi ? tC : 0.f);
  int nposC = Pi ? (cnt[l + 1] - 1) : 0;
  bool anyv = (cntNI - ((l != -1) ? 1 : 0)) > 0;
  if (Pi && nposC > 0 && anyv) {
    float lse = logf(Sc);
    float lossC = -(SP - (float)nposC * lse) / fmaxf((float)nposC, 1.f);
    numC = lossC * w; denC = w;
  }
  float v0 = numF, v1 = denF, v2 = numC, v3 = denC;
  #pragma unroll
  for (int m = 1; m < 64; m <<= 1) {
    v0 += __shfl_xor(v0, m); v1 += __shfl_xor(v1, m);
    v2 += __shfl_xor(v2, m); v3 += __shfl_xor(v3, m);
  }
  __shared__ float red[4][4];
  int lane = threadIdx.x & 63, wid = threadIdx.x >> 6;
  if (lane == 0) { red[wid][0]=v0; red[wid][1]=v1; red[wid][2]=v2; red[wid][3]=v3; }
  __syncthreads();
  if (threadIdx.x == 0) {
    float s0=0,s1=0,s2=0,s3=0;
    for (int q = 0; q < 4; ++q) { s0+=red[q][0]; s1+=red[q][1]; s2+=red[q][2]; s3+=red[q][3]; }
    atomicAdd(&accum[0], s0); atomicAdd(&accum[1], s1);
    atomicAdd(&accum[2], s2); atomicAdd(&accum[3], s3);
    __threadfence();
    int t = atomicAdd(&cnt[22], 1);
    if (t == 31) {
      __threadfence();
      out[0] = accum[0] / (accum[1] + 1e-8f);
      out[1] = accum[2] / (accum[3] + 1e-12f);
    }
  }
}

extern "C" void kernel_launch(void* const* d_in, const int* in_sizes, int n_in,
                              void* d_out, int out_size, void* d_ws, size_t ws_size,
                              hipStream_t stream) {
  const float* X    = (const float*)d_in[0];
  const int*  labels= (const int*)d_in[1];
  const float* ious = (const float*)d_in[2];
  const float* w1f  = (const float*)d_in[3];
  const float* b1f  = (const float*)d_in[4];
  const float* w2f  = (const float*)d_in[5];
  const float* b2f  = (const float*)d_in[6];
  const float* w1c  = (const float*)d_in[7];
  const float* b1c  = (const float*)d_in[8];
  const float* w2c  = (const float*)d_in[9];
  const float* b2c  = (const float*)d_in[10];
  float* out = (float*)d_out;

  char* w = (char*)d_ws;
  short* W1pf = (short*)w;            w += 524288;
  short* W1pc = (short*)w;            w += 524288;
  short* W2pf = (short*)w;            w += 32768;
  short* W2pc = (short*)w;            w += 65536;
  short* Zrf  = (short*)w;            w += 1048576;
  short* Zrc  = (short*)w;            w += 2097152;
  float* Sfg  = (float*)w;            w += 32768;
  float* Pfg  = (float*)w;            w += 32768;
  float* Scls = (float*)w;            w += 32768;
  float* SPc  = (float*)w;            w += 32768;
  float* tiif = (float*)w;            w += 32768;
  float* tiic = (float*)w;            w += 32768;
  float* pfv  = (float*)w;            w += 32768;
  float* nimv = (float*)w;            w += 32768;
  float* ljmv = (float*)w;            w += 32768;
  float* accum= (float*)w;            w += 32;
  int*   cnt  = (int*)w;              w += 96;

  pack_zero_kernel<<<281, 256, 0, stream>>>(w1f, w1c, w2f, w2c,
                                            W1pf, W1pc, W2pf, W2pc, accum, cnt);

  fused_mlp_kernel<<<dim3(256, 2), 256, 0, stream>>>(X, W1pf, W1pc, b1f, b1c,
                                            W2pf, W2pc, b2f, b2c,
                                            Zrf, Zrc, tiif, tiic,
                                            labels, Sfg, Pfg, Scls, SPc,
                                            pfv, nimv, ljmv, cnt);

  loss_kernel<<<dim3(64, 16), 512, 0, stream>>>(Zrf, Zrc, labels, pfv, nimv, ljmv,
                                                Sfg, Pfg, Scls, SPc);

  finalize_kernel<<<N_ROI/256, 256, 0, stream>>>(Sfg, Pfg, Scls, SPc, tiif, tiic,
                                                 labels, ious, cnt, accum, out);
}

// Round 4
// 184.894 us; speedup vs baseline: 1.0286x; 1.0286x over previous
//
#include <hip/hip_runtime.h>
#include <hip/hip_bf16.h>
#include <math.h>

#define N_ROI 8192
#define C_IN  1024
#define HIDD  256
#define FGD   64
#define CLSD  128
#define INV_TAU 5.0f
#define SCALE_LOG2E 7.2134752f   // 5 * log2(e)
#define LN2F 0.69314718f

using frag_ab = __attribute__((ext_vector_type(8))) short;   // 8 bf16 = 4 VGPRs
using f32x16  = __attribute__((ext_vector_type(16))) float;

static __device__ __forceinline__ short f32_to_bf16_bits(float f) {
  unsigned u = __builtin_bit_cast(unsigned, f);
  u = (u + 0x7FFFu + ((u >> 16) & 1u)) >> 16;   // RNE (inputs finite)
  return (short)u;
}
static __device__ __forceinline__ float bf16_bits_to_f32(short b) {
  unsigned u = ((unsigned)(unsigned short)b) << 16;
  return __builtin_bit_cast(float, u);
}
static __device__ __forceinline__ float fast_exp2(float x) {
#if __has_builtin(__builtin_amdgcn_exp2f)
  return __builtin_amdgcn_exp2f(x);
#else
  return exp2f(x);
#endif
}
// async global->LDS, 16B per lane. LDS dest = wave-uniform base + lane*16.
static __device__ __forceinline__ void async_copy16(const void* g, void* l) {
  __builtin_amdgcn_global_load_lds(
      (const __attribute__((address_space(1))) unsigned int*)g,
      (__attribute__((address_space(3))) unsigned int*)l, 16, 0, 0);
}

// ---------------- L1: pack weights (fp32 -> bf16 frag order) + zero accum/cnt ------
__global__ __launch_bounds__(256) void pack_zero_kernel(
    const float* __restrict__ w1f, const float* __restrict__ w1c,
    const float* __restrict__ w2f, const float* __restrict__ w2c,
    short* __restrict__ W1pf, short* __restrict__ W1pc,
    short* __restrict__ W2pf, short* __restrict__ W2pc,
    float* __restrict__ accum, int* __restrict__ cnt) {
  int b = blockIdx.x;
  if (b == 280) {
    int t = threadIdx.x;
    if (t < 8) accum[t] = 0.f;
    if (t < 24) cnt[t] = 0;
    return;
  }
  const float* src; short* dst; int Ksh; int b0;
  if (b < 128)      { src = w1f; dst = W1pf; Ksh = 10; b0 = 0; }
  else if (b < 256) { src = w1c; dst = W1pc; Ksh = 10; b0 = 128; }
  else if (b < 264) { src = w2f; dst = W2pf; Ksh = 8;  b0 = 256; }
  else              { src = w2c; dst = W2pc; Ksh = 8;  b0 = 264; }
  int K = 1 << Ksh;
  int f = (b - b0) * 256 + threadIdx.x;
  int r = f >> (Ksh - 3);
  int c0 = (f & ((K >> 3) - 1)) << 3;
  float4 v0 = *(const float4*)(src + (size_t)r * K + c0);
  float4 v1 = *(const float4*)(src + (size_t)r * K + c0 + 4);
  union { short s[8]; uint4 v; } o;
  o.s[0] = f32_to_bf16_bits(v0.x); o.s[1] = f32_to_bf16_bits(v0.y);
  o.s[2] = f32_to_bf16_bits(v0.z); o.s[3] = f32_to_bf16_bits(v0.w);
  o.s[4] = f32_to_bf16_bits(v1.x); o.s[5] = f32_to_bf16_bits(v1.y);
  o.s[6] = f32_to_bf16_bits(v1.z); o.s[7] = f32_to_bf16_bits(v1.w);
  ((uint4*)dst)[(size_t)((r >> 5) * (K >> 4) + (c0 >> 4)) * 64 +
                ((c0 >> 3) & 1) * 32 + (r & 31)] = o.v;
}

// ---------------- phase-2 helper: gemm2+normalize+pack from LDS H tile ----------
// Single wave, no barriers. T2 row-major H: T2[r*264 + c], c in [0,256).
template<int D>
__device__ __forceinline__ void gemm2_from_lds(
    const short* __restrict__ T2,
    const short* __restrict__ W2p, const float* __restrict__ b2,
    short* __restrict__ Zr, float* __restrict__ tii,
    short* __restrict__ T, int gt) {
  int lane = threadIdx.x & 63;
  const frag_ab* Wv = (const frag_ab*)W2p;
  constexpr int NT = D / 32;
  frag_ab a[16];
  #pragma unroll
  for (int kc = 0; kc < 16; ++kc)
    a[kc] = *(const frag_ab*)&T2[(lane & 31) * 264 + kc * 16 + (lane >> 5) * 8];
  f32x16 acc[NT];
  #pragma unroll
  for (int j = 0; j < NT; ++j)
    #pragma unroll
    for (int q = 0; q < 16; ++q) acc[j][q] = 0.f;
  #pragma unroll
  for (int kc = 0; kc < 16; ++kc)
    #pragma unroll
    for (int j = 0; j < NT; ++j)
      acc[j] = __builtin_amdgcn_mfma_f32_32x32x16_bf16(a[kc], Wv[(j * 16 + kc) * 64 + lane], acc[j], 0, 0, 0);
  int c = lane & 31, h = lane >> 5;
  float bb[NT];
  #pragma unroll
  for (int j = 0; j < NT; ++j) bb[j] = b2[j * 32 + c];
  float s1[16];
  #pragma unroll
  for (int r = 0; r < 16; ++r) {
    s1[r] = 0.f;
    #pragma unroll
    for (int j = 0; j < NT; ++j) {
      float v = acc[j][r] + bb[j];
      s1[r] += v * v;
    }
  }
  #pragma unroll
  for (int r = 0; r < 16; ++r)
    #pragma unroll
    for (int m = 1; m < 32; m <<= 1) s1[r] += __shfl_xor(s1[r], m);
  float s2[16];
  #pragma unroll
  for (int r = 0; r < 16; ++r) s2[r] = 0.f;
  #pragma unroll
  for (int j = 0; j < NT; ++j) {
    int cl = j * 32 + c;
    #pragma unroll
    for (int g = 0; g < 4; ++g) {
      short q0, q1, q2, q3;
      #pragma unroll
      for (int e = 0; e < 4; ++e) {
        int r = g * 4 + e;
        float sc = 1.f / fmaxf(sqrtf(s1[r]), 1e-8f);
        short qb = f32_to_bf16_bits((acc[j][r] + bb[j]) * sc);
        float zf = bf16_bits_to_f32(qb);
        s2[r] += zf * zf;
        if (e == 0) q0 = qb; else if (e == 1) q1 = qb; else if (e == 2) q2 = qb; else q3 = qb;
      }
      *(short4*)&T[cl * 36 + 4 * h + 8 * g] = make_short4(q0, q1, q2, q3);
    }
  }
  #pragma unroll
  for (int r = 0; r < 16; ++r)
    #pragma unroll
    for (int m = 1; m < 32; m <<= 1) s2[r] += __shfl_xor(s2[r], m);
  if (c == 0) {
    #pragma unroll
    for (int r = 0; r < 16; ++r)
      tii[gt * 32 + (r & 3) + 8 * (r >> 2) + 4 * h] = s2[r];
  }
  uint4* Zv = (uint4*)Zr;
  #pragma unroll
  for (int k = 0; k < D / 16; ++k) {
    int c0 = (2 * k + h) * 8;
    union { short s[8]; uint4 u; } o;
    #pragma unroll
    for (int e = 0; e < 8; ++e) o.s[e] = T[(c0 + e) * 36 + c];
    Zv[(size_t)(gt * (D / 16) + k) * 64 + h * 32 + c] = o.u;
  }
}

// ---------------- L2: fused MLP — drain-free k-loop, deep register prefetch ------
// The old loop's __syncthreads (= s_waitcnt vmcnt(0)+barrier) drained the 1-step
// prefetch every k-step -> each step paid full HBM latency on X. Now: raw
// s_barrier with lgkmcnt(0) only (LDS handoff needs no vmem drain); X loads run
// 4 steps ahead (av ring), W loads 2 steps ahead (3 breg banks). Compiler's
// per-register vmcnt waits give ~3 steps (~1000 cy) of load slack. Arithmetic
// (addresses, MFMA order, conversions) is identical to the previous version.
__global__ __launch_bounds__(256) void fused_mlp_kernel(
    const float* __restrict__ X,
    const short* __restrict__ W1pf, const short* __restrict__ W1pc,
    const float* __restrict__ b1f, const float* __restrict__ b1c,
    const short* __restrict__ W2pf, const short* __restrict__ W2pc,
    const float* __restrict__ b2f, const float* __restrict__ b2c,
    short* __restrict__ Zrf, short* __restrict__ Zrc,
    float* __restrict__ tiif, float* __restrict__ tiic,
    const int* __restrict__ labels,
    float* __restrict__ Sfg, float* __restrict__ Pfg,
    float* __restrict__ Scls, float* __restrict__ SPc,
    float* __restrict__ pfv, float* __restrict__ nimv,
    float* __restrict__ ljmv, int* __restrict__ cnt) {
  __shared__ short stageA[2][1024];     // 4 KB
  __shared__ short T2[32 * 264];        // 16.9 KB row-major H (this head)
  __shared__ short Tw[128 * 36];        // 9.2 KB phase-2 transpose
  int tid = threadIdx.x, lane = tid & 63, wv = tid >> 6;
  int Mb = blockIdx.x, head = blockIdx.y;

  if (head == 0 && tid < 32) {
    int i = Mb * 32 + tid;
    Sfg[i] = 0.f; Pfg[i] = 0.f; Scls[i] = 0.f; SPc[i] = 0.f;
    int l = labels[i];
    pfv[i]  = (l > 0)  ? 1.f : 0.f;
    nimv[i] = (l != -1) ? 1.f : 0.f;
    ljmv[i] = (l > 0)  ? (float)l : -7.f;
    int b = l + 1; if (b < 0) b = 0; if (b > 21) b = 21;
    atomicAdd(&cnt[b], 1);
  }

  const short* Wp = head ? W1pc : W1pf;
  const float* b1 = head ? b1c  : b1f;
  const uint4* Wv4 = (const uint4*)Wp;
  int arow = tid >> 3;
  int ac4  = tid & 7;
  const float* Xp = X + (size_t)(Mb * 32 + arow) * C_IN + ac4 * 4;
  int aslot = ((ac4 >> 2) * 64 + ((ac4 >> 1) & 1) * 32 + arow) * 8 + (ac4 & 1) * 4;

  float4 av[4];                         // 4-deep X prefetch ring
  frag_ab breg[3][4];                   // 3 W banks = 2-step prefetch
  f32x16 acc[2];
  #pragma unroll
  for (int nt = 0; nt < 2; ++nt)
    #pragma unroll
    for (int q = 0; q < 16; ++q) acc[nt][q] = 0.f;

  auto loadA = [&](int c, int s) { av[s] = *(const float4*)(Xp + c * 32); };
  auto loadB = [&](int c, int s) {
    #pragma unroll
    for (int kci = 0; kci < 2; ++kci)
      #pragma unroll
      for (int nt = 0; nt < 2; ++nt)
        breg[s][kci * 2 + nt] =
            *(const frag_ab*)&Wv4[(size_t)((wv * 2 + nt) * 64 + c * 2 + kci) * 64 + lane];
  };
  auto storeA = [&](int buf, int s) {
    *(short4*)&stageA[buf][aslot] =
        make_short4(f32_to_bf16_bits(av[s].x), f32_to_bf16_bits(av[s].y),
                    f32_to_bf16_bits(av[s].z), f32_to_bf16_bits(av[s].w));
  };
  auto domfma = [&](int buf, int bank) {
    frag_ab a0 = *(const frag_ab*)&stageA[buf][(0 * 64 + lane) * 8];
    frag_ab a1 = *(const frag_ab*)&stageA[buf][(1 * 64 + lane) * 8];
    #pragma unroll
    for (int nt = 0; nt < 2; ++nt)
      acc[nt] = __builtin_amdgcn_mfma_f32_32x32x16_bf16(a0, breg[bank][nt], acc[nt], 0, 0, 0);
    #pragma unroll
    for (int nt = 0; nt < 2; ++nt)
      acc[nt] = __builtin_amdgcn_mfma_f32_32x32x16_bf16(a1, breg[bank][2 + nt], acc[nt], 0, 0, 0);
  };
  // LDS-handoff barrier: lgkmcnt(0) covers this wave's ds_write AND retires its
  // ds_reads (so the other buffer may be overwritten after the barrier). No
  // vmcnt drain -> global prefetches stay in flight across the barrier.
  auto lds_barrier = [&]() {
    asm volatile("s_waitcnt lgkmcnt(0)" ::: "memory");
    __builtin_amdgcn_s_barrier();
    __builtin_amdgcn_sched_barrier(0);
  };

  loadA(0, 0); loadA(1, 1); loadA(2, 2); loadA(3, 3);
  loadB(0, 0); loadB(1, 1);
  storeA(0, 0);                         // compiler waits av[0] only
  lds_barrier();

  #pragma unroll
  for (int c = 0; c < 32; ++c) {
    if (c + 2 < 32) loadB(c + 2, (c + 2) % 3);
    if (c + 4 < 32) loadA(c + 4, (c + 4) & 3);
    domfma(c & 1, c % 3);
    if (c + 1 < 32) {
      storeA((c + 1) & 1, (c + 1) & 3);
      lds_barrier();
    }
  }
  {
    int cl31 = lane & 31, h = lane >> 5;
    #pragma unroll
    for (int nt = 0; nt < 2; ++nt) {
      int gc = wv * 64 + nt * 32 + cl31;
      float bb = b1[gc];
      #pragma unroll
      for (int q = 0; q < 16; ++q) {
        int row = (q & 3) + 8 * (q >> 2) + 4 * h;
        float x = fmaxf(acc[nt][q] + bb, 0.f);
        T2[row * 264 + gc] = f32_to_bf16_bits(x);
      }
    }
  }
  __syncthreads();

  if (wv == 0) {
    if (head == 0)
      gemm2_from_lds<FGD>(T2, W2pf, b2f, Zrf, tiif, Tw, Mb);
    else
      gemm2_from_lds<CLSD>(T2, W2pc, b2c, Zrc, tiic, Tw, Mb);
  }
}

// ---------------- L3: MFMA Gram loss — 512-thread blocks, 8 waves share tiles ----
template<int D, int MODE, int NJT>
__device__ __forceinline__ void loss_body(
    const short* __restrict__ Zr, const int* __restrict__ labels,
    const float* __restrict__ pfv, const float* __restrict__ nimv,
    const float* __restrict__ ljmv,
    float* __restrict__ Sg, float* __restrict__ Pg,
    short* __restrict__ smem) {
  constexpr int KC = D / 16;              // 4 (fg) or 8 (cls)
  constexpr int JP = (MODE == 0) ? 2 : 1; // j-tiles per iteration
  constexpr int NIT = NJT / JP;           // iterations: 8 (fg) or 16 (cls)
  constexpr int BUF_SH = 4096;            // shorts per 8 KB buffer
  int tid = threadIdx.x, lane = tid & 63, wv = tid >> 6;   // wv in 0..7
  int itile = (blockIdx.x >> 1) * 8 + wv;
  int jt0 = blockIdx.y * NJT;
  int jlane = lane & 31;
  const frag_ab* Zrv = (const frag_ab*)Zr;

  // A fragments (rescaled to log2-domain)
  frag_ab a[KC];
  #pragma unroll
  for (int kc = 0; kc < KC; ++kc) {
    frag_ab t = Zrv[(itile * KC + kc) * 64 + lane];
    #pragma unroll
    for (int e = 0; e < 8; ++e)
      t[e] = f32_to_bf16_bits(bf16_bits_to_f32(t[e]) * SCALE_LOG2E);
    a[kc] = t;
  }
  float limf[16];
  if (MODE == 1) {
    #pragma unroll
    for (int r = 0; r < 16; ++r) {
      int row = (r & 3) + 8 * (r >> 2) + 4 * (lane >> 5);
      limf[r] = (float)labels[itile * 32 + row];
    }
  }
  // Pin prologue register loads before the drain so later vmcnt counts are exact.
  __builtin_amdgcn_sched_barrier(0);
  asm volatile("s_waitcnt vmcnt(0)" ::: "memory");
  __builtin_amdgcn_sched_barrier(0);

  short* b0 = smem;
  short* b1 = smem + BUF_SH;
  short* b2 = smem + 2 * BUF_SH;
  float* maskf = (float*)(smem + 3 * BUF_SH);   // 512 (MODE0) / 1024 (MODE1) floats

  // stage masks: exactly 1 global_load_lds per wave (waves 2-7 / 4-7 redundant)
  if (MODE == 0) {
    async_copy16(pfv + jt0 * 32 + (size_t)(tid & 127) * 4,
                 maskf + (wv & 1) * 256);
  } else {
    const float* msrc = ((wv & 2) == 0) ? nimv : ljmv;
    float* mdst = maskf + ((wv & 2) ? 512 : 0) + (wv & 1) * 256;
    async_copy16(msrc + jt0 * 32 + (size_t)(tid & 127) * 4, mdst);
  }

  // stage iteration quantum: 8 KB linear (one cls tile / one fg tile pair)
  auto STAGE = [&](short* dst, int it) {
    const short* src = Zr + (size_t)(jt0 + it * JP) * KC * 512 / JP * JP;
    async_copy16(src + (size_t)tid * 8, dst + wv * 512);
  };

  STAGE(b0, 0); STAGE(b1, 1);

  float Ssum[16] = {}, Psum[16] = {};

  #pragma unroll 1
  for (int t = 0; t < NIT; ++t) {
    if (t < NIT - 1) asm volatile("s_waitcnt vmcnt(1)" ::: "memory");
    else             asm volatile("s_waitcnt vmcnt(0)" ::: "memory");
    __builtin_amdgcn_s_barrier();
    __builtin_amdgcn_sched_barrier(0);
    if (t + 2 < NIT) STAGE(b2, t + 2);

    if (MODE == 0) {
      float pf0 = maskf[t * 64 + jlane];
      float pf1 = maskf[t * 64 + 32 + jlane];
      f32x16 acc0, acc1;
      #pragma unroll
      for (int q = 0; q < 16; ++q) { acc0[q] = 0.f; acc1[q] = 0.f; }
      __builtin_amdgcn_s_setprio(1);
      #pragma unroll
      for (int kc = 0; kc < KC; ++kc) {
        frag_ab bb0 = *(const frag_ab*)&b0[(kc * 64 + lane) * 8];
        frag_ab bb1 = *(const frag_ab*)&b0[((KC + kc) * 64 + lane) * 8];
        acc0 = __builtin_amdgcn_mfma_f32_32x32x16_bf16(a[kc], bb0, acc0, 0, 0, 0);
        acc1 = __builtin_amdgcn_mfma_f32_32x32x16_bf16(a[kc], bb1, acc1, 0, 0, 0);
      }
      __builtin_amdgcn_s_setprio(0);
      #pragma unroll
      for (int rr = 0; rr < 16; ++rr) {
        float e0 = fast_exp2(acc0[rr]);
        float e1 = fast_exp2(acc1[rr]);
        Ssum[rr] += e0 + e1;
        Psum[rr] = fmaf(pf0, e0, fmaf(pf1, e1, Psum[rr]));
      }
    } else {
      float nim = maskf[t * 32 + jlane];
      float ljm = maskf[512 + t * 32 + jlane];
      f32x16 acc;
      #pragma unroll
      for (int q = 0; q < 16; ++q) acc[q] = 0.f;
      __builtin_amdgcn_s_setprio(1);
      #pragma unroll
      for (int kc = 0; kc < KC; ++kc) {
        frag_ab b = *(const frag_ab*)&b0[(kc * 64 + lane) * 8];
        acc = __builtin_amdgcn_mfma_f32_32x32x16_bf16(a[kc], b, acc, 0, 0, 0);
      }
      __builtin_amdgcn_s_setprio(0);
      #pragma unroll
      for (int rr = 0; rr < 16; ++rr) {
        float e = fast_exp2(acc[rr]);
        Ssum[rr] = fmaf(nim, e, Ssum[rr]);
        Psum[rr] += (limf[rr] == ljm) ? acc[rr] : 0.f;
      }
    }
    short* tmp = b0; b0 = b1; b1 = b2; b2 = tmp;   // rotate
  }

  #pragma unroll
  for (int r = 0; r < 16; ++r) {
    float s = Ssum[r], p = Psum[r];
    #pragma unroll
    for (int m = 1; m < 32; m <<= 1) { s += __shfl_xor(s, m); p += __shfl_xor(p, m); }
    if ((lane & 31) == 0) {
      if (MODE == 1) p *= LN2F;
      int row = (r & 3) + 8 * (r >> 2) + 4 * (lane >> 5);
      atomicAdd(&Sg[itile * 32 + row], s);
      atomicAdd(&Pg[itile * 32 + row], p);
    }
  }
}

__global__ __launch_bounds__(512, 2) void loss_kernel(
    const short* __restrict__ Zrf, const short* __restrict__ Zrc,
    const int* __restrict__ labels,
    const float* __restrict__ pfv, const float* __restrict__ nimv,
    const float* __restrict__ ljmv,
    float* __restrict__ Sfg, float* __restrict__ Pfg,
    float* __restrict__ Scls, float* __restrict__ SPc) {
  // 3 x 8 KB rotating buffers + mask region (1024 floats) = 28 KB
  __shared__ short smem[3 * 4096 + 2048];
  if ((blockIdx.x & 1) == 0)
    loss_body<FGD, 0, 16>(Zrf, labels, pfv, nimv, ljmv, Sfg, Pfg, smem);
  else
    loss_body<CLSD, 1, 16>(Zrc, labels, pfv, nimv, ljmv, Scls, SPc, smem);
}

// ---------------- L4: per-row losses + weighted reduction + write-out ------------
__global__ __launch_bounds__(256) void finalize_kernel(
    const float* __restrict__ Sfg, const float* __restrict__ Pfg,
    const float* __restrict__ Scls, const float* __restrict__ SPc,
    const float* __restrict__ tiif, const float* __restrict__ tiic,
    const int* __restrict__ labels, const float* __restrict__ ious,
    int* __restrict__ cnt, float* __restrict__ accum, float* __restrict__ out) {
  int i = blockIdx.x * 256 + threadIdx.x;
  int l = labels[i];
  float iv = ious[i];
  float w = (iv > 0.5f) ? iv : 0.f;
  int cntP = 0;
  #pragma unroll
  for (int b = 2; b <= 21; ++b) cntP += cnt[b];
  int cntNI = N_ROI - cnt[0];
  bool Pi = (l > 0);
  float numF = 0.f, denF = 0.f, numC = 0.f, denC = 0.f;
  float eF = __expf(INV_TAU * tiif[i]);
  float Sf = Sfg[i] - eF;
  float Pf = Pfg[i] - (Pi ? eF : 0.f);
  int nposF = cntP - (Pi ? 1 : 0);
  if (Pi && nposF > 0) {
    float lossF = logf((Sf + 1e-8f) / (Pf + 1e-8f));
    numF = lossF * w; denF = w;
  }
  float tC = INV_TAU * tiic[i];
  float eC = __expf(tC);
  float Sc = Scls[i] - ((l != -1) ? eC : 0.f);
  float SP = SPc[i] - (Pi ? tC : 0.f);
  int nposC = Pi ? (cnt[l + 1] - 1) : 0;
  bool anyv = (cntNI - ((l != -1) ? 1 : 0)) > 0;
  if (Pi && nposC > 0 && anyv) {
    float lse = logf(Sc);
    float lossC = -(SP - (float)nposC * lse) / fmaxf((float)nposC, 1.f);
    numC = lossC * w; denC = w;
  }
  float v0 = numF, v1 = denF, v2 = numC, v3 = denC;
  #pragma unroll
  for (int m = 1; m < 64; m <<= 1) {
    v0 += __shfl_xor(v0, m); v1 += __shfl_xor(v1, m);
    v2 += __shfl_xor(v2, m); v3 += __shfl_xor(v3, m);
  }
  __shared__ float red[4][4];
  int lane = threadIdx.x & 63, wid = threadIdx.x >> 6;
  if (lane == 0) { red[wid][0]=v0; red[wid][1]=v1; red[wid][2]=v2; red[wid][3]=v3; }
  __syncthreads();
  if (threadIdx.x == 0) {
    float s0=0,s1=0,s2=0,s3=0;
    for (int q = 0; q < 4; ++q) { s0+=red[q][0]; s1+=red[q][1]; s2+=red[q][2]; s3+=red[q][3]; }
    atomicAdd(&accum[0], s0); atomicAdd(&accum[1], s1);
    atomicAdd(&accum[2], s2); atomicAdd(&accum[3], s3);
    __threadfence();
    int t = atomicAdd(&cnt[22], 1);
    if (t == 31) {
      __threadfence();
      out[0] = accum[0] / (accum[1] + 1e-8f);
      out[1] = accum[2] / (accum[3] + 1e-12f);
    }
  }
}

extern "C" void kernel_launch(void* const* d_in, const int* in_sizes, int n_in,
                              void* d_out, int out_size, void* d_ws, size_t ws_size,
                              hipStream_t stream) {
  const float* X    = (const float*)d_in[0];
  const int*  labels= (const int*)d_in[1];
  const float* ious = (const float*)d_in[2];
  const float* w1f  = (const float*)d_in[3];
  const float* b1f  = (const float*)d_in[4];
  const float* w2f  = (const float*)d_in[5];
  const float* b2f  = (const float*)d_in[6];
  const float* w1c  = (const float*)d_in[7];
  const float* b1c  = (const float*)d_in[8];
  const float* w2c  = (const float*)d_in[9];
  const float* b2c  = (const float*)d_in[10];
  float* out = (float*)d_out;

  char* w = (char*)d_ws;
  short* W1pf = (short*)w;            w += 524288;
  short* W1pc = (short*)w;            w += 524288;
  short* W2pf = (short*)w;            w += 32768;
  short* W2pc = (short*)w;            w += 65536;
  short* Zrf  = (short*)w;            w += 1048576;
  short* Zrc  = (short*)w;            w += 2097152;
  float* Sfg  = (float*)w;            w += 32768;
  float* Pfg  = (float*)w;            w += 32768;
  float* Scls = (float*)w;            w += 32768;
  float* SPc  = (float*)w;            w += 32768;
  float* tiif = (float*)w;            w += 32768;
  float* tiic = (float*)w;            w += 32768;
  float* pfv  = (float*)w;            w += 32768;
  float* nimv = (float*)w;            w += 32768;
  float* ljmv = (float*)w;            w += 32768;
  float* accum= (float*)w;            w += 32;
  int*   cnt  = (int*)w;              w += 96;

  pack_zero_kernel<<<281, 256, 0, stream>>>(w1f, w1c, w2f, w2c,
                                            W1pf, W1pc, W2pf, W2pc, accum, cnt);

  fused_mlp_kernel<<<dim3(256, 2), 256, 0, stream>>>(X, W1pf, W1pc, b1f, b1c,
                                            W2pf, W2pc, b2f, b2c,
                                            Zrf, Zrc, tiif, tiic,
                                            labels, Sfg, Pfg, Scls, SPc,
                                            pfv, nimv, ljmv, cnt);

  loss_kernel<<<dim3(64, 16), 512, 0, stream>>>(Zrf, Zrc, labels, pfv, nimv, ljmv,
                                                Sfg, Pfg, Scls, SPc);

  finalize_kernel<<<N_ROI/256, 256, 0, stream>>>(Sfg, Pfg, Scls, SPc, tiif, tiic,
                                                 labels, ious, cnt, accum, out);
}

// Round 5
// 184.254 us; speedup vs baseline: 1.0322x; 1.0035x over previous
//
#include <hip/hip_runtime.h>
#include <hip/hip_bf16.h>
#include <math.h>

#define N_ROI 8192
#define C_IN  1024
#define HIDD  256
#define FGD   64
#define CLSD  128
#define INV_TAU 5.0f
#define SCALE_LOG2E 7.2134752f   // 5 * log2(e)
#define LN2F 0.69314718f

using frag_ab = __attribute__((ext_vector_type(8))) short;   // 8 bf16 = 4 VGPRs
using f32x16  = __attribute__((ext_vector_type(16))) float;

static __device__ __forceinline__ short f32_to_bf16_bits(float f) {
  unsigned u = __builtin_bit_cast(unsigned, f);
  u = (u + 0x7FFFu + ((u >> 16) & 1u)) >> 16;   // RNE (inputs finite)
  return (short)u;
}
static __device__ __forceinline__ float bf16_bits_to_f32(short b) {
  unsigned u = ((unsigned)(unsigned short)b) << 16;
  return __builtin_bit_cast(float, u);
}
static __device__ __forceinline__ float fast_exp2(float x) {
#if __has_builtin(__builtin_amdgcn_exp2f)
  return __builtin_amdgcn_exp2f(x);
#else
  return exp2f(x);
#endif
}
// async global->LDS, 16B per lane. LDS dest = wave-uniform base + lane*16.
static __device__ __forceinline__ void async_copy16(const void* g, void* l) {
  __builtin_amdgcn_global_load_lds(
      (const __attribute__((address_space(1))) unsigned int*)g,
      (__attribute__((address_space(3))) unsigned int*)l, 16, 0, 0);
}

// ---------------- L1: pack weights (fp32 -> bf16 frag order) + zero accum/cnt/Vc --
__global__ __launch_bounds__(256) void pack_zero_kernel(
    const float* __restrict__ w1f, const float* __restrict__ w1c,
    const float* __restrict__ w2f, const float* __restrict__ w2c,
    short* __restrict__ W1pf, short* __restrict__ W1pc,
    short* __restrict__ W2pf, short* __restrict__ W2pc,
    float* __restrict__ accum, int* __restrict__ cnt,
    float* __restrict__ Vc) {
  int b = blockIdx.x;
  if (b == 280) {
    int t = threadIdx.x;
    if (t < 8) accum[t] = 0.f;
    if (t < 24) cnt[t] = 0;
    for (int q = t; q < 2560; q += 256) Vc[q] = 0.f;
    return;
  }
  const float* src; short* dst; int Ksh; int b0;
  if (b < 128)      { src = w1f; dst = W1pf; Ksh = 10; b0 = 0; }
  else if (b < 256) { src = w1c; dst = W1pc; Ksh = 10; b0 = 128; }
  else if (b < 264) { src = w2f; dst = W2pf; Ksh = 8;  b0 = 256; }
  else              { src = w2c; dst = W2pc; Ksh = 8;  b0 = 264; }
  int K = 1 << Ksh;
  int f = (b - b0) * 256 + threadIdx.x;
  int r = f >> (Ksh - 3);
  int c0 = (f & ((K >> 3) - 1)) << 3;
  float4 v0 = *(const float4*)(src + (size_t)r * K + c0);
  float4 v1 = *(const float4*)(src + (size_t)r * K + c0 + 4);
  union { short s[8]; uint4 v; } o;
  o.s[0] = f32_to_bf16_bits(v0.x); o.s[1] = f32_to_bf16_bits(v0.y);
  o.s[2] = f32_to_bf16_bits(v0.z); o.s[3] = f32_to_bf16_bits(v0.w);
  o.s[4] = f32_to_bf16_bits(v1.x); o.s[5] = f32_to_bf16_bits(v1.y);
  o.s[6] = f32_to_bf16_bits(v1.z); o.s[7] = f32_to_bf16_bits(v1.w);
  ((uint4*)dst)[(size_t)((r >> 5) * (K >> 4) + (c0 >> 4)) * 64 +
                ((c0 >> 3) & 1) * 32 + (r & 31)] = o.v;
}

// ---------------- phase-2 helper: gemm2+normalize+pack from LDS H tile ----------
// Single wave, no barriers. T2 row-major H: T2[r*264 + c], c in [0,256).
template<int D>
__device__ __forceinline__ void gemm2_from_lds(
    const short* __restrict__ T2,
    const short* __restrict__ W2p, const float* __restrict__ b2,
    short* __restrict__ Zr, float* __restrict__ tii,
    short* __restrict__ T, int gt) {
  int lane = threadIdx.x & 63;
  const frag_ab* Wv = (const frag_ab*)W2p;
  constexpr int NT = D / 32;
  frag_ab a[16];
  #pragma unroll
  for (int kc = 0; kc < 16; ++kc)
    a[kc] = *(const frag_ab*)&T2[(lane & 31) * 264 + kc * 16 + (lane >> 5) * 8];
  f32x16 acc[NT];
  #pragma unroll
  for (int j = 0; j < NT; ++j)
    #pragma unroll
    for (int q = 0; q < 16; ++q) acc[j][q] = 0.f;
  #pragma unroll
  for (int kc = 0; kc < 16; ++kc)
    #pragma unroll
    for (int j = 0; j < NT; ++j)
      acc[j] = __builtin_amdgcn_mfma_f32_32x32x16_bf16(a[kc], Wv[(j * 16 + kc) * 64 + lane], acc[j], 0, 0, 0);
  int c = lane & 31, h = lane >> 5;
  float bb[NT];
  #pragma unroll
  for (int j = 0; j < NT; ++j) bb[j] = b2[j * 32 + c];
  float s1[16];
  #pragma unroll
  for (int r = 0; r < 16; ++r) {
    s1[r] = 0.f;
    #pragma unroll
    for (int j = 0; j < NT; ++j) {
      float v = acc[j][r] + bb[j];
      s1[r] += v * v;
    }
  }
  #pragma unroll
  for (int r = 0; r < 16; ++r)
    #pragma unroll
    for (int m = 1; m < 32; m <<= 1) s1[r] += __shfl_xor(s1[r], m);
  float s2[16];
  #pragma unroll
  for (int r = 0; r < 16; ++r) s2[r] = 0.f;
  #pragma unroll
  for (int j = 0; j < NT; ++j) {
    int cl = j * 32 + c;
    #pragma unroll
    for (int g = 0; g < 4; ++g) {
      short q0, q1, q2, q3;
      #pragma unroll
      for (int e = 0; e < 4; ++e) {
        int r = g * 4 + e;
        float sc = 1.f / fmaxf(sqrtf(s1[r]), 1e-8f);
        short qb = f32_to_bf16_bits((acc[j][r] + bb[j]) * sc);
        float zf = bf16_bits_to_f32(qb);
        s2[r] += zf * zf;
        if (e == 0) q0 = qb; else if (e == 1) q1 = qb; else if (e == 2) q2 = qb; else q3 = qb;
      }
      *(short4*)&T[cl * 36 + 4 * h + 8 * g] = make_short4(q0, q1, q2, q3);
    }
  }
  #pragma unroll
  for (int r = 0; r < 16; ++r)
    #pragma unroll
    for (int m = 1; m < 32; m <<= 1) s2[r] += __shfl_xor(s2[r], m);
  if (c == 0) {
    #pragma unroll
    for (int r = 0; r < 16; ++r)
      tii[gt * 32 + (r & 3) + 8 * (r >> 2) + 4 * h] = s2[r];
  }
  uint4* Zv = (uint4*)Zr;
  #pragma unroll
  for (int k = 0; k < D / 16; ++k) {
    int c0 = (2 * k + h) * 8;
    union { short s[8]; uint4 u; } o;
    #pragma unroll
    for (int e = 0; e < 8; ++e) o.s[e] = T[(c0 + e) * 36 + c];
    Zv[(size_t)(gt * (D / 16) + k) * 64 + h * 32 + c] = o.u;
  }
}

// ---------------- L2: fused MLP — drain-free k-loop, deep register prefetch ------
__global__ __launch_bounds__(256) void fused_mlp_kernel(
    const float* __restrict__ X,
    const short* __restrict__ W1pf, const short* __restrict__ W1pc,
    const float* __restrict__ b1f, const float* __restrict__ b1c,
    const short* __restrict__ W2pf, const short* __restrict__ W2pc,
    const float* __restrict__ b2f, const float* __restrict__ b2c,
    short* __restrict__ Zrf, short* __restrict__ Zrc,
    float* __restrict__ tiif, float* __restrict__ tiic,
    const int* __restrict__ labels,
    float* __restrict__ Sfg, float* __restrict__ Pfg,
    float* __restrict__ Scls,
    float* __restrict__ pfv, float* __restrict__ nimv,
    int* __restrict__ cnt) {
  __shared__ short stageA[2][1024];     // 4 KB
  __shared__ short T2[32 * 264];        // 16.9 KB row-major H (this head)
  __shared__ short Tw[128 * 36];        // 9.2 KB phase-2 transpose
  int tid = threadIdx.x, lane = tid & 63, wv = tid >> 6;
  int Mb = blockIdx.x, head = blockIdx.y;

  if (head == 0 && tid < 32) {
    int i = Mb * 32 + tid;
    Sfg[i] = 0.f; Pfg[i] = 0.f; Scls[i] = 0.f;
    int l = labels[i];
    pfv[i]  = (l > 0)  ? 1.f : 0.f;
    nimv[i] = (l != -1) ? 1.f : 0.f;
    int b = l + 1; if (b < 0) b = 0; if (b > 21) b = 21;
    atomicAdd(&cnt[b], 1);
  }

  const short* Wp = head ? W1pc : W1pf;
  const float* b1 = head ? b1c  : b1f;
  const uint4* Wv4 = (const uint4*)Wp;
  int arow = tid >> 3;
  int ac4  = tid & 7;
  const float* Xp = X + (size_t)(Mb * 32 + arow) * C_IN + ac4 * 4;
  int aslot = ((ac4 >> 2) * 64 + ((ac4 >> 1) & 1) * 32 + arow) * 8 + (ac4 & 1) * 4;

  float4 av[4];                         // 4-deep X prefetch ring
  frag_ab breg[3][4];                   // 3 W banks = 2-step prefetch
  f32x16 acc[2];
  #pragma unroll
  for (int nt = 0; nt < 2; ++nt)
    #pragma unroll
    for (int q = 0; q < 16; ++q) acc[nt][q] = 0.f;

  auto loadA = [&](int c, int s) { av[s] = *(const float4*)(Xp + c * 32); };
  auto loadB = [&](int c, int s) {
    #pragma unroll
    for (int kci = 0; kci < 2; ++kci)
      #pragma unroll
      for (int nt = 0; nt < 2; ++nt)
        breg[s][kci * 2 + nt] =
            *(const frag_ab*)&Wv4[(size_t)((wv * 2 + nt) * 64 + c * 2 + kci) * 64 + lane];
  };
  auto storeA = [&](int buf, int s) {
    *(short4*)&stageA[buf][aslot] =
        make_short4(f32_to_bf16_bits(av[s].x), f32_to_bf16_bits(av[s].y),
                    f32_to_bf16_bits(av[s].z), f32_to_bf16_bits(av[s].w));
  };
  auto domfma = [&](int buf, int bank) {
    frag_ab a0 = *(const frag_ab*)&stageA[buf][(0 * 64 + lane) * 8];
    frag_ab a1 = *(const frag_ab*)&stageA[buf][(1 * 64 + lane) * 8];
    #pragma unroll
    for (int nt = 0; nt < 2; ++nt)
      acc[nt] = __builtin_amdgcn_mfma_f32_32x32x16_bf16(a0, breg[bank][nt], acc[nt], 0, 0, 0);
    #pragma unroll
    for (int nt = 0; nt < 2; ++nt)
      acc[nt] = __builtin_amdgcn_mfma_f32_32x32x16_bf16(a1, breg[bank][2 + nt], acc[nt], 0, 0, 0);
  };
  auto lds_barrier = [&]() {
    asm volatile("s_waitcnt lgkmcnt(0)" ::: "memory");
    __builtin_amdgcn_s_barrier();
    __builtin_amdgcn_sched_barrier(0);
  };

  loadA(0, 0); loadA(1, 1); loadA(2, 2); loadA(3, 3);
  loadB(0, 0); loadB(1, 1);
  storeA(0, 0);
  lds_barrier();

  #pragma unroll
  for (int c = 0; c < 32; ++c) {
    if (c + 2 < 32) loadB(c + 2, (c + 2) % 3);
    if (c + 4 < 32) loadA(c + 4, (c + 4) & 3);
    domfma(c & 1, c % 3);
    if (c + 1 < 32) {
      storeA((c + 1) & 1, (c + 1) & 3);
      lds_barrier();
    }
  }
  {
    int cl31 = lane & 31, h = lane >> 5;
    #pragma unroll
    for (int nt = 0; nt < 2; ++nt) {
      int gc = wv * 64 + nt * 32 + cl31;
      float bb = b1[gc];
      #pragma unroll
      for (int q = 0; q < 16; ++q) {
        int row = (q & 3) + 8 * (q >> 2) + 4 * h;
        float x = fmaxf(acc[nt][q] + bb, 0.f);
        T2[row * 264 + gc] = f32_to_bf16_bits(x);
      }
    }
  }
  __syncthreads();

  if (wv == 0) {
    if (head == 0)
      gemm2_from_lds<FGD>(T2, W2pf, b2f, Zrf, tiif, Tw, Mb);
    else
      gemm2_from_lds<CLSD>(T2, W2pc, b2c, Zrc, tiic, Tw, Mb);
  }
}

// ---------------- L2b: per-class z-sums Vc[c][d] = sum_{lab_j=c} z_cls[j][d] -----
// SP[i] = z_i . Vc[lab_i] * INV_TAU  (exact decomposition of the same-label sim
// sum — exp is only needed for the LSE denominator, so the O(N^2) cls loop no
// longer carries the label-compare Psum path). Row list built once in LDS so the
// per-dim accumulation loop has no label-dependent branches on its critical path.
__global__ __launch_bounds__(128) void classsum_kernel(
    const short* __restrict__ Zrc, const int* __restrict__ labels,
    float* __restrict__ Vc) {
  __shared__ int lidx[512];
  __shared__ int lcnt;
  int c = blockIdx.x + 1;               // class 1..20
  int d = threadIdx.x;                  // dim 0..127
  int j0 = blockIdx.y * 512;
  if (d == 0) lcnt = 0;
  __syncthreads();
  #pragma unroll
  for (int u = 0; u < 4; ++u) {
    int row = j0 + u * 128 + d;
    if (labels[row] == c) {
      int k = atomicAdd(&lcnt, 1);
      lidx[k] = row;
    }
  }
  __syncthreads();
  int n = lcnt;
  int kc = d >> 4, h = (d >> 3) & 1, e = d & 7;
  float acc = 0.f;
  for (int k = 0; k < n; ++k) {
    int row = lidx[k];
    int jt = row >> 5, r = row & 31;
    acc += bf16_bits_to_f32(
        Zrc[((size_t)((jt * 8 + kc) * 64 + h * 32 + r)) * 8 + e]);
  }
  atomicAdd(&Vc[(c - 1) * 128 + d], acc);
}

// ---------------- L3: MFMA Gram loss — JP=2, cls Psum removed -------------------
// Both modes: 2 j-tiles/iteration (2 independent MFMA chains), NIT=8 barriers,
// 3 rotating buffers, counted vmcnt. MODE0 (fg): Ssum (unmasked) + pf-weighted
// Psum. MODE1 (cls): nim-weighted Ssum only (SP handled by classsum+finalize).
// cls Ssum accumulation order matches the old sequential-tile order exactly.
template<int D, int MODE, int NJT>
__device__ __forceinline__ void loss_body(
    const short* __restrict__ Zr,
    const float* __restrict__ maskv,
    float* __restrict__ Sg, float* __restrict__ Pg,
    short* __restrict__ smem) {
  constexpr int KC = D / 16;              // 4 (fg) or 8 (cls)
  constexpr int JP = 2;
  constexpr int NIT = NJT / JP;           // 8
  constexpr int BUFQ = JP * KC * 512;     // shorts per buffer (fg 4096, cls 8192)
  constexpr int LD = BUFQ / 4096;         // async copies per wave per STAGE (1/2)
  int tid = threadIdx.x, lane = tid & 63, wv = tid >> 6;   // wv in 0..7
  int itile = (blockIdx.x >> 1) * 8 + wv;
  int jt0 = blockIdx.y * NJT;
  int jlane = lane & 31;
  const frag_ab* Zrv = (const frag_ab*)Zr;

  // A fragments (rescaled to log2-domain)
  frag_ab a[KC];
  #pragma unroll
  for (int kc = 0; kc < KC; ++kc) {
    frag_ab t = Zrv[(itile * KC + kc) * 64 + lane];
    #pragma unroll
    for (int e = 0; e < 8; ++e)
      t[e] = f32_to_bf16_bits(bf16_bits_to_f32(t[e]) * SCALE_LOG2E);
    a[kc] = t;
  }
  // Pin prologue register loads before the drain so later vmcnt counts are exact.
  __builtin_amdgcn_sched_barrier(0);
  asm volatile("s_waitcnt vmcnt(0)" ::: "memory");
  __builtin_amdgcn_sched_barrier(0);

  short* b0 = smem;
  short* b1 = smem + BUFQ;
  short* b2 = smem + 2 * BUFQ;
  float* maskf = (float*)(smem + 3 * BUFQ);   // NJT*32 = 512 floats

  // stage mask: exactly 1 global_load_lds per wave (waves 2-7 redundant)
  async_copy16(maskv + jt0 * 32 + (size_t)(tid & 127) * 4,
               maskf + (wv & 1) * 256);

  auto STAGE = [&](short* dst, int it) {
    const short* src = Zr + (size_t)(jt0 + it * JP) * KC * 512;
    #pragma unroll
    for (int u = 0; u < LD; ++u)
      async_copy16(src + (size_t)(u * 512 + tid) * 8, dst + u * 4096 + wv * 512);
  };

  STAGE(b0, 0); STAGE(b1, 1);

  float Ssum[16] = {}, Psum[16] = {};

  #pragma unroll 1
  for (int t = 0; t < NIT; ++t) {
    if (t < NIT - 1) {
      if constexpr (LD == 1) asm volatile("s_waitcnt vmcnt(1)" ::: "memory");
      else                   asm volatile("s_waitcnt vmcnt(2)" ::: "memory");
    } else {
      asm volatile("s_waitcnt vmcnt(0)" ::: "memory");
    }
    __builtin_amdgcn_s_barrier();
    __builtin_amdgcn_sched_barrier(0);
    if (t + 2 < NIT) STAGE(b2, t + 2);

    float m0 = maskf[t * 64 + jlane];
    float m1 = maskf[t * 64 + 32 + jlane];
    f32x16 acc0, acc1;
    #pragma unroll
    for (int q = 0; q < 16; ++q) { acc0[q] = 0.f; acc1[q] = 0.f; }
    #pragma unroll
    for (int kc = 0; kc < KC; ++kc) {
      frag_ab bb0 = *(const frag_ab*)&b0[(kc * 64 + lane) * 8];
      frag_ab bb1 = *(const frag_ab*)&b0[((KC + kc) * 64 + lane) * 8];
      acc0 = __builtin_amdgcn_mfma_f32_32x32x16_bf16(a[kc], bb0, acc0, 0, 0, 0);
      acc1 = __builtin_amdgcn_mfma_f32_32x32x16_bf16(a[kc], bb1, acc1, 0, 0, 0);
    }
    #pragma unroll
    for (int rr = 0; rr < 16; ++rr) {
      float e0 = fast_exp2(acc0[rr]);
      float e1 = fast_exp2(acc1[rr]);
      if (MODE == 0) {
        Ssum[rr] += e0 + e1;
        Psum[rr] = fmaf(m0, e0, fmaf(m1, e1, Psum[rr]));
      } else {
        Ssum[rr] = fmaf(m1, e1, fmaf(m0, e0, Ssum[rr]));
      }
    }
    short* tmp = b0; b0 = b1; b1 = b2; b2 = tmp;   // rotate
  }

  #pragma unroll
  for (int r = 0; r < 16; ++r) {
    float s = Ssum[r], p = Psum[r];
    #pragma unroll
    for (int m = 1; m < 32; m <<= 1) {
      s += __shfl_xor(s, m);
      if (MODE == 0) p += __shfl_xor(p, m);
    }
    if ((lane & 31) == 0) {
      int row = (r & 3) + 8 * (r >> 2) + 4 * (lane >> 5);
      atomicAdd(&Sg[itile * 32 + row], s);
      if (MODE == 0) atomicAdd(&Pg[itile * 32 + row], p);
    }
  }
}

__global__ __launch_bounds__(512, 2) void loss_kernel(
    const short* __restrict__ Zrf, const short* __restrict__ Zrc,
    const float* __restrict__ pfv, const float* __restrict__ nimv,
    float* __restrict__ Sfg, float* __restrict__ Pfg,
    float* __restrict__ Scls) {
  // 3 x 16 KB rotating buffers (cls size) + mask region = 51.2 KB
  __shared__ short smem[3 * 8192 + 1024];
  if ((blockIdx.x & 1) == 0)
    loss_body<FGD, 0, 16>(Zrf, pfv, Sfg, Pfg, smem);
  else
    loss_body<CLSD, 1, 16>(Zrc, nimv, Scls, nullptr, smem);
}

// ---------------- L4: per-row losses + weighted reduction + write-out ------------
__global__ __launch_bounds__(256) void finalize_kernel(
    const float* __restrict__ Sfg, const float* __restrict__ Pfg,
    const float* __restrict__ Scls,
    const short* __restrict__ Zrc, const float* __restrict__ Vc,
    const float* __restrict__ tiif, const float* __restrict__ tiic,
    const int* __restrict__ labels, const float* __restrict__ ious,
    int* __restrict__ cnt, float* __restrict__ accum, float* __restrict__ out) {
  int i = blockIdx.x * 256 + threadIdx.x;
  int l = labels[i];
  float iv = ious[i];
  float w = (iv > 0.5f) ? iv : 0.f;
  int cntP = 0;
  #pragma unroll
  for (int b = 2; b <= 21; ++b) cntP += cnt[b];
  int cntNI = N_ROI - cnt[0];
  bool Pi = (l > 0);
  float numF = 0.f, denF = 0.f, numC = 0.f, denC = 0.f;
  float eF = __expf(INV_TAU * tiif[i]);
  float Sf = Sfg[i] - eF;
  float Pf = Pfg[i] - (Pi ? eF : 0.f);
  int nposF = cntP - (Pi ? 1 : 0);
  if (Pi && nposF > 0) {
    float lossF = logf((Sf + 1e-8f) / (Pf + 1e-8f));
    numF = lossF * w; denF = w;
  }
  float tC = INV_TAU * tiic[i];
  float eC = __expf(tC);
  float Sc = Scls[i] - ((l != -1) ? eC : 0.f);
  // SP via class-sum decomposition: z_i . Vc[lab_i] * INV_TAU, minus self sim.
  float SPdot = 0.f;
  if (Pi) {
    const float* V = Vc + (size_t)(l - 1) * 128;
    int jt = i >> 5, r = i & 31;
    #pragma unroll
    for (int kc = 0; kc < 8; ++kc)
      #pragma unroll
      for (int h = 0; h < 2; ++h) {
        frag_ab z = *(const frag_ab*)&Zrc[((size_t)((jt * 8 + kc) * 64 + h * 32 + r)) * 8];
        #pragma unroll
        for (int e = 0; e < 8; ++e)
          SPdot += bf16_bits_to_f32(z[e]) * V[kc * 16 + h * 8 + e];
      }
  }
  float SP = SPdot * INV_TAU - (Pi ? tC : 0.f);
  int nposC = Pi ? (cnt[l + 1] - 1) : 0;
  bool anyv = (cntNI - ((l != -1) ? 1 : 0)) > 0;
  if (Pi && nposC > 0 && anyv) {
    float lse = logf(Sc);
    float lossC = -(SP - (float)nposC * lse) / fmaxf((float)nposC, 1.f);
    numC = lossC * w; denC = w;
  }
  float v0 = numF, v1 = denF, v2 = numC, v3 = denC;
  #pragma unroll
  for (int m = 1; m < 64; m <<= 1) {
    v0 += __shfl_xor(v0, m); v1 += __shfl_xor(v1, m);
    v2 += __shfl_xor(v2, m); v3 += __shfl_xor(v3, m);
  }
  __shared__ float red[4][4];
  int lane = threadIdx.x & 63, wid = threadIdx.x >> 6;
  if (lane == 0) { red[wid][0]=v0; red[wid][1]=v1; red[wid][2]=v2; red[wid][3]=v3; }
  __syncthreads();
  if (threadIdx.x == 0) {
    float s0=0,s1=0,s2=0,s3=0;
    for (int q = 0; q < 4; ++q) { s0+=red[q][0]; s1+=red[q][1]; s2+=red[q][2]; s3+=red[q][3]; }
    atomicAdd(&accum[0], s0); atomicAdd(&accum[1], s1);
    atomicAdd(&accum[2], s2); atomicAdd(&accum[3], s3);
    __threadfence();
    int t = atomicAdd(&cnt[22], 1);
    if (t == 31) {
      __threadfence();
      out[0] = accum[0] / (accum[1] + 1e-8f);
      out[1] = accum[2] / (accum[3] + 1e-12f);
    }
  }
}

extern "C" void kernel_launch(void* const* d_in, const int* in_sizes, int n_in,
                              void* d_out, int out_size, void* d_ws, size_t ws_size,
                              hipStream_t stream) {
  const float* X    = (const float*)d_in[0];
  const int*  labels= (const int*)d_in[1];
  const float* ious = (const float*)d_in[2];
  const float* w1f  = (const float*)d_in[3];
  const float* b1f  = (const float*)d_in[4];
  const float* w2f  = (const float*)d_in[5];
  const float* b2f  = (const float*)d_in[6];
  const float* w1c  = (const float*)d_in[7];
  const float* b1c  = (const float*)d_in[8];
  const float* w2c  = (const float*)d_in[9];
  const float* b2c  = (const float*)d_in[10];
  float* out = (float*)d_out;

  char* w = (char*)d_ws;
  short* W1pf = (short*)w;            w += 524288;
  short* W1pc = (short*)w;            w += 524288;
  short* W2pf = (short*)w;            w += 32768;
  short* W2pc = (short*)w;            w += 65536;
  short* Zrf  = (short*)w;            w += 1048576;
  short* Zrc  = (short*)w;            w += 2097152;
  float* Sfg  = (float*)w;            w += 32768;
  float* Pfg  = (float*)w;            w += 32768;
  float* Scls = (float*)w;            w += 32768;
  float* SPc  = (float*)w;            w += 32768;   // unused (kept for layout)
  float* tiif = (float*)w;            w += 32768;
  float* tiic = (float*)w;            w += 32768;
  float* pfv  = (float*)w;            w += 32768;
  float* nimv = (float*)w;            w += 32768;
  float* ljmv = (float*)w;            w += 32768;   // unused (kept for layout)
  float* accum= (float*)w;            w += 32;
  int*   cnt  = (int*)w;              w += 96;
  float* Vc   = (float*)w;            w += 10240;   // 20 classes x 128 dims f32
  (void)SPc; (void)ljmv;

  pack_zero_kernel<<<281, 256, 0, stream>>>(w1f, w1c, w2f, w2c,
                                            W1pf, W1pc, W2pf, W2pc, accum, cnt, Vc);

  fused_mlp_kernel<<<dim3(256, 2), 256, 0, stream>>>(X, W1pf, W1pc, b1f, b1c,
                                            W2pf, W2pc, b2f, b2c,
                                            Zrf, Zrc, tiif, tiic,
                                            labels, Sfg, Pfg, Scls,
                                            pfv, nimv, cnt);

  classsum_kernel<<<dim3(20, 16), 128, 0, stream>>>(Zrc, labels, Vc);

  loss_kernel<<<dim3(64, 16), 512, 0, stream>>>(Zrf, Zrc, pfv, nimv,
                                                Sfg, Pfg, Scls);

  finalize_kernel<<<N_ROI/256, 256, 0, stream>>>(Sfg, Pfg, Scls, Zrc, Vc,
                                                 tiif, tiic,
                                                 labels, ious, cnt, accum, out);
}